// Round 1
// baseline (2040.067 us; speedup 1.0000x reference)
//
#include <hip/hip_runtime.h>
#include <hip/hip_bf16.h>
#include <stdint.h>

#define NB 64
#define NT 256
#define NH 768

typedef float f32x4 __attribute__((ext_vector_type(4)));
typedef __bf16 bf16x8 __attribute__((ext_vector_type(8)));

static __device__ __forceinline__ uint16_t f2bf(float f) {
  union { float f; uint32_t u; } v; v.f = f;
  uint32_t r = v.u + 0x7FFFu + ((v.u >> 16) & 1u);
  return (uint16_t)(r >> 16);
}
static __device__ __forceinline__ float bf2f(uint16_t h) {
  union { uint32_t u; float f; } v; v.u = ((uint32_t)h) << 16;
  return v.f;
}

// ---------------------------------------------------------------------------
// Prep: transpose+cast weights. Wc1T/Wc2T: [T,H] bf16; WbT hi/lo: [H,H] bf16.
__global__ void prep_weights(const float* __restrict__ Wc1,
                             const float* __restrict__ Wc2,
                             const float* __restrict__ Wb,
                             uint16_t* __restrict__ Wc1T, uint16_t* __restrict__ Wc2T,
                             uint16_t* __restrict__ WbTh, uint16_t* __restrict__ WbTl) {
  int idx = blockIdx.x * 256 + threadIdx.x;
  if (idx < NT * NH) {
    int i = idx / NH, h = idx % NH;
    Wc1T[idx] = f2bf(Wc1[h * NT + i]);
    Wc2T[idx] = f2bf(Wc2[h * NT + i]);
  }
  if (idx < NH * NH) {
    int n = idx / NH, k = idx % NH;
    float w = Wb[k * NH + n];
    uint16_t hi = f2bf(w);
    WbTh[idx] = hi;
    WbTl[idx] = f2bf(w - bf2f(hi));
  }
}

// Split q,p into bf16 hi/lo; pd = bf16(p * Wd[h]).
__global__ void prep_qp(const float* __restrict__ q, const float* __restrict__ p,
                        const float* __restrict__ Wd,
                        uint16_t* __restrict__ q_hi, uint16_t* __restrict__ q_lo,
                        uint16_t* __restrict__ p_hi, uint16_t* __restrict__ p_lo,
                        uint16_t* __restrict__ pd) {
  long idx = (long)blockIdx.x * 256 + threadIdx.x;
  if (idx >= (long)NB * NT * NH) return;
  int h = (int)(idx % NH);
  float qv = q[idx], pv = p[idx];
  uint16_t qh = f2bf(qv);
  q_hi[idx] = qh; q_lo[idx] = f2bf(qv - bf2f(qh));
  uint16_t ph = f2bf(pv);
  p_hi[idx] = ph; p_lo[idx] = f2bf(pv - bf2f(ph));
  pd[idx] = f2bf(pv * Wd[h]);
}

// qT[b,h,t] = q_hi[b,t,h]  (LDS-tiled transpose, 32x32 tiles)
__global__ void transpose_q(const uint16_t* __restrict__ q_hi, uint16_t* __restrict__ qT) {
  __shared__ uint16_t tile[32][33];
  int b = blockIdx.z;
  int h0 = blockIdx.x * 32, t0 = blockIdx.y * 32;
  int tx = threadIdx.x & 31, ty = threadIdx.x >> 5;  // ty in [0,8)
  const uint16_t* src = q_hi + ((long)b * NT + t0) * NH + h0;
  for (int s = 0; s < 32; s += 8) tile[ty + s][tx] = src[(long)(ty + s) * NH + tx];
  __syncthreads();
  uint16_t* dst = qT + ((long)b * NH + h0) * NT + t0;
  for (int s = 0; s < 32; s += 8) dst[(long)(ty + s) * NT + tx] = tile[tx][ty + s];
}

// qWm[b,t] = q[b,t,:]·Wm ; pWm[b,t] = p[b,t,:]·Wm  (f32 exact)
__global__ void gemv_wm(const float* __restrict__ q, const float* __restrict__ p,
                        const float* __restrict__ Wm,
                        float* __restrict__ qWm, float* __restrict__ pWm) {
  int wave = (blockIdx.x * 256 + (int)threadIdx.x) >> 6;
  int lane = threadIdx.x & 63;
  const int nrows = NB * NT;
  const float* src = (wave < nrows) ? q : p;
  float* dst = (wave < nrows) ? qWm : pWm;
  int row = (wave < nrows) ? wave : wave - nrows;
  const float* rp = src + (long)row * NH;
  float s = 0.f;
  for (int h = lane; h < NH; h += 64) s += rp[h] * Wm[h];
  for (int off = 32; off; off >>= 1) s += __shfl_down(s, off);
  if (lane == 0) dst[row] = s;
}

// ---------------------------------------------------------------------------
// Batched NT GEMM: C[b] = sum_t A_t[b] (M,K) * B_t[b] (N,K)^T, bf16 MFMA 16x16x32.
// Up to 3 A/B pairs accumulated (for hi/lo split precision).
// outmode: 0 = f32, 1 = bf16, 2 = bf16 hi/lo split to C0/C1.
__global__ __launch_bounds__(256) void gemm_nt(
    const uint16_t* __restrict__ A0, const uint16_t* __restrict__ A1,
    const uint16_t* __restrict__ A2,
    const uint16_t* __restrict__ B0, const uint16_t* __restrict__ B1,
    const uint16_t* __restrict__ B2,
    int npairs, long sA, long sB,
    int M, int N, int K, int lda, int ldb,
    int outmode, void* C0v, void* C1v, long sC, int ldc) {
  int b = blockIdx.z;
  int wave = (int)(threadIdx.x >> 6);
  int lane = (int)(threadIdx.x & 63);
  int r = lane & 15, quad = lane >> 4;
  int m0 = blockIdx.y * 32 + (wave >> 1) * 16;
  int n0 = blockIdx.x * 32 + (wave & 1) * 16;
  if (m0 >= M || n0 >= N) return;
  f32x4 acc = {0.f, 0.f, 0.f, 0.f};
  for (int t = 0; t < npairs; ++t) {
    const uint16_t* Ap = (t == 0) ? A0 : ((t == 1) ? A1 : A2);
    const uint16_t* Bp = (t == 0) ? B0 : ((t == 1) ? B1 : B2);
    const uint16_t* Arow = Ap + (long)b * sA + (long)(m0 + r) * lda + quad * 8;
    const uint16_t* Brow = Bp + (long)b * sB + (long)(n0 + r) * ldb + quad * 8;
#pragma unroll 4
    for (int k = 0; k < K; k += 32) {
      bf16x8 av = *(const bf16x8*)(Arow + k);
      bf16x8 bv = *(const bf16x8*)(Brow + k);
      acc = __builtin_amdgcn_mfma_f32_16x16x32_bf16(av, bv, acc, 0, 0, 0);
    }
  }
  // C/D frag: col = lane&15, row = quad*4 + t   [verified m89/m91]
  int row = m0 + quad * 4;
  int col = n0 + r;
  if (outmode == 0) {
    float* C = (float*)C0v + (long)b * sC;
#pragma unroll
    for (int t = 0; t < 4; ++t) C[(long)(row + t) * ldc + col] = acc[t];
  } else if (outmode == 1) {
    uint16_t* C = (uint16_t*)C0v + (long)b * sC;
#pragma unroll
    for (int t = 0; t < 4; ++t) C[(long)(row + t) * ldc + col] = f2bf(acc[t]);
  } else {
    uint16_t* Ch = (uint16_t*)C0v + (long)b * sC;
    uint16_t* Cl = (uint16_t*)C1v + (long)b * sC;
#pragma unroll
    for (int t = 0; t < 4; ++t) {
      float v = acc[t];
      uint16_t hi = f2bf(v);
      Ch[(long)(row + t) * ldc + col] = hi;
      Cl[(long)(row + t) * ldc + col] = f2bf(v - bf2f(hi));
    }
  }
}

// ---------------------------------------------------------------------------
// Assemble the 4 score rows for (b,i), softmax over j, emit bf16 P matrices.
// P layout: 4 contiguous [NB,NT,NT] blocks in order c,b,d,m.
__global__ __launch_bounds__(256) void softmax_k(
    const uint16_t* __restrict__ whp, const uint16_t* __restrict__ whqT,
    const float* __restrict__ sb, const uint16_t* __restrict__ sd,
    const float* __restrict__ qWm, const float* __restrict__ pWm,
    const float* __restrict__ vc, const float* __restrict__ vd,
    const float* __restrict__ vm,
    uint16_t* __restrict__ P) {
  __shared__ float red[256];
  int bi = blockIdx.x;  // b*NT + i
  int b = bi >> 8, i = bi & 255;
  int j = threadIdx.x;
  long off = (long)bi * NT + j;
  // sc[b,i,j] = tanh(whp[b,i,j] + whq[b,j,i]) * vc[i]        (vc per-i)
  float s0 = tanhf(bf2f(whp[off]) + bf2f(whqT[off])) * vc[i];
  // sb raw (no tanh)
  float s1 = sb[off];
  // sd[b,i,j] = tanh(sd_raw) * vd[j]                         (vd per-j!)
  float s2 = tanhf(bf2f(sd[off])) * vd[j];
  // sm[b,i,j] = tanh(qWm[b,j] - pWm[b,i]) * vm[j]            (vm per-j!)
  float s3 = tanhf(qWm[(long)b * NT + j] - pWm[(long)b * NT + i]) * vm[j];
  float ss[4] = {s0, s1, s2, s3};
  const long PB = (long)NB * NT * NT;
#pragma unroll
  for (int a = 0; a < 4; ++a) {
    float s = ss[a];
    red[j] = s; __syncthreads();
    for (int st = 128; st > 0; st >>= 1) {
      if (j < st) red[j] = fmaxf(red[j], red[j + st]);
      __syncthreads();
    }
    float mx = red[0]; __syncthreads();
    float e = __expf(s - mx);
    red[j] = e; __syncthreads();
    for (int st = 128; st > 0; st >>= 1) {
      if (j < st) red[j] += red[j + st];
      __syncthreads();
    }
    float sum = red[0]; __syncthreads();
    P[a * PB + off] = f2bf(e / sum);
  }
}

// ---------------------------------------------------------------------------
extern "C" void kernel_launch(void* const* d_in, const int* in_sizes, int n_in,
                              void* d_out, int out_size, void* d_ws, size_t ws_size,
                              hipStream_t stream) {
  const float* q   = (const float*)d_in[0];
  const float* p   = (const float*)d_in[1];
  const float* Wc1 = (const float*)d_in[2];
  const float* Wc2 = (const float*)d_in[3];
  const float* vc  = (const float*)d_in[4];
  const float* Wb  = (const float*)d_in[5];
  const float* Wd  = (const float*)d_in[6];
  const float* vd  = (const float*)d_in[7];
  const float* Wm  = (const float*)d_in[8];
  const float* vm  = (const float*)d_in[9];
  (void)in_sizes; (void)n_in; (void)out_size; (void)ws_size;

  char* ws = (char*)d_ws;
  size_t o = 0;
  auto alloc = [&](size_t bytes) -> char* {
    char* r = ws + o;
    o = (o + bytes + 255) & ~(size_t)255;
    return r;
  };
  const size_t nqp = (size_t)NB * NT * NH;   // 12.58M
  const size_t ntt = (size_t)NB * NT * NT;   // 4.19M

  uint16_t* Wc1T = (uint16_t*)alloc((size_t)NT * NH * 2);
  uint16_t* Wc2T = (uint16_t*)alloc((size_t)NT * NH * 2);
  uint16_t* WbTh = (uint16_t*)alloc((size_t)NH * NH * 2);
  uint16_t* WbTl = (uint16_t*)alloc((size_t)NH * NH * 2);
  uint16_t* q_hi = (uint16_t*)alloc(nqp * 2);
  uint16_t* q_lo = (uint16_t*)alloc(nqp * 2);
  uint16_t* p_hi = (uint16_t*)alloc(nqp * 2);
  uint16_t* p_lo = (uint16_t*)alloc(nqp * 2);
  uint16_t* pd   = (uint16_t*)alloc(nqp * 2);
  uint16_t* qT   = (uint16_t*)alloc(nqp * 2);
  float*    qWmB = (float*)alloc((size_t)NB * NT * 4);
  float*    pWmB = (float*)alloc((size_t)NB * NT * 4);
  uint16_t* whp  = (uint16_t*)alloc(ntt * 2);
  uint16_t* whqT = (uint16_t*)alloc(ntt * 2);
  uint16_t* pWbh = (uint16_t*)alloc(nqp * 2);
  uint16_t* pWbl = (uint16_t*)alloc(nqp * 2);
  float*    sbuf = (float*)alloc(ntt * 4);
  uint16_t* sd   = (uint16_t*)alloc(ntt * 2);
  uint16_t* P    = (uint16_t*)alloc(4 * ntt * 2);

  const long sQP = (long)NT * NH;  // per-batch stride of q/p/pWb/qT/out
  const long sTT = (long)NT * NT;

  prep_weights<<<dim3((NH * NH + 255) / 256), dim3(256), 0, stream>>>(
      Wc1, Wc2, Wb, Wc1T, Wc2T, WbTh, WbTl);
  prep_qp<<<dim3((unsigned)((nqp + 255) / 256)), dim3(256), 0, stream>>>(
      q, p, Wd, q_hi, q_lo, p_hi, p_lo, pd);
  transpose_q<<<dim3(NH / 32, NT / 32, NB), dim3(256), 0, stream>>>(q_hi, qT);
  gemv_wm<<<dim3(2 * NB * NT / 4), dim3(256), 0, stream>>>(q, p, Wm, qWmB, pWmB);

  // whqT[b,i,j] = sum_h Wc1[h,i] q[b,j,h]   (A = Wc1T shared, B = q_hi batched)
  gemm_nt<<<dim3(8, 8, NB), dim3(256), 0, stream>>>(
      Wc1T, nullptr, nullptr, q_hi, nullptr, nullptr, 1,
      0L, sQP, 256, 256, 768, NH, NH, 1, whqT, nullptr, sTT, NT);

  // whp[b,i,j] = sum_h p[b,i,h] Wc2[h,j]    (A = p_hi batched, B = Wc2T shared)
  gemm_nt<<<dim3(8, 8, NB), dim3(256), 0, stream>>>(
      p_hi, nullptr, nullptr, Wc2T, nullptr, nullptr, 1,
      sQP, 0L, 256, 256, 768, NH, NH, 1, whp, nullptr, sTT, NT);

  // pWb = p @ Wb with hi/lo split (3 products), epilogue re-splits to hi/lo bf16
  gemm_nt<<<dim3(24, 8, NB), dim3(256), 0, stream>>>(
      p_hi, p_hi, p_lo, WbTh, WbTl, WbTh, 3,
      sQP, 0L, 256, 768, 768, NH, NH, 2, pWbh, pWbl, sQP, NH);

  // sb = pWb @ q^T with hi/lo split (3 products), f32 out (precision-critical)
  gemm_nt<<<dim3(8, 8, NB), dim3(256), 0, stream>>>(
      pWbh, pWbh, pWbl, q_hi, q_lo, q_hi, 3,
      sQP, sQP, 256, 256, 768, NH, NH, 0, sbuf, nullptr, sTT, NT);

  // sd_raw = (p*Wd) @ q^T
  gemm_nt<<<dim3(8, 8, NB), dim3(256), 0, stream>>>(
      pd, nullptr, nullptr, q_hi, nullptr, nullptr, 1,
      sQP, sQP, 256, 256, 768, NH, NH, 1, sd, nullptr, sTT, NT);

  softmax_k<<<dim3(NB * NT), dim3(256), 0, stream>>>(
      whp, whqT, sbuf, sd, qWmB, pWmB, vc, vd, vm, P);

  // PV: out_a = P_a @ q   (A = P_a [T,T], B = qT [H,T] per batch)
  float* out = (float*)d_out;
  for (int a = 0; a < 4; ++a) {
    gemm_nt<<<dim3(24, 8, NB), dim3(256), 0, stream>>>(
        P + (size_t)a * ntt, nullptr, nullptr, qT, nullptr, nullptr, 1,
        sTT, sQP, 256, 768, 256, NT, NT, 0, out + (size_t)a * nqp, nullptr, sQP, NH);
  }
}

// Round 2
// 705.331 us; speedup vs baseline: 2.8924x; 2.8924x over previous
//
#include <hip/hip_runtime.h>
#include <hip/hip_bf16.h>
#include <stdint.h>

#define NB 64
#define NT 256
#define NH 768

#define BM 128
#define BN 128
#define BK 32

typedef float f32x4 __attribute__((ext_vector_type(4)));
typedef __bf16 bf16x8 __attribute__((ext_vector_type(8)));

static __device__ __forceinline__ uint16_t f2bf(float f) {
  union { float f; uint32_t u; } v; v.f = f;
  uint32_t r = v.u + 0x7FFFu + ((v.u >> 16) & 1u);
  return (uint16_t)(r >> 16);
}
static __device__ __forceinline__ float bf2f(uint16_t h) {
  union { uint32_t u; float f; } v; v.u = ((uint32_t)h) << 16;
  return v.f;
}

// global -> LDS direct DMA, 16B per lane. LDS dest = wave-uniform base + lane*16.
typedef const __attribute__((address_space(1))) uint32_t* gp1_t;
typedef __attribute__((address_space(3))) uint32_t* lp3_t;
static __device__ __forceinline__ void gload_lds16(const uint16_t* g, uint16_t* l) {
  __builtin_amdgcn_global_load_lds((gp1_t)g, (lp3_t)l, 16, 0, 0);
}

// ---------------------------------------------------------------------------
// Prep: transpose+cast weights. Wc1T/Wc2T: [T,H] bf16; WbT hi/lo: [H,H] bf16.
__global__ void prep_weights(const float* __restrict__ Wc1,
                             const float* __restrict__ Wc2,
                             const float* __restrict__ Wb,
                             uint16_t* __restrict__ Wc1T, uint16_t* __restrict__ Wc2T,
                             uint16_t* __restrict__ WbTh, uint16_t* __restrict__ WbTl) {
  int idx = blockIdx.x * 256 + threadIdx.x;
  if (idx < NT * NH) {
    int i = idx / NH, h = idx % NH;
    Wc1T[idx] = f2bf(Wc1[h * NT + i]);
    Wc2T[idx] = f2bf(Wc2[h * NT + i]);
  }
  if (idx < NH * NH) {
    int n = idx / NH, k = idx % NH;
    float w = Wb[k * NH + n];
    uint16_t hi = f2bf(w);
    WbTh[idx] = hi;
    WbTl[idx] = f2bf(w - bf2f(hi));
  }
}

// Split q,p into bf16 hi/lo; pd = bf16(p * Wd[h]).
__global__ void prep_qp(const float* __restrict__ q, const float* __restrict__ p,
                        const float* __restrict__ Wd,
                        uint16_t* __restrict__ q_hi, uint16_t* __restrict__ q_lo,
                        uint16_t* __restrict__ p_hi, uint16_t* __restrict__ p_lo,
                        uint16_t* __restrict__ pd) {
  long idx = (long)blockIdx.x * 256 + threadIdx.x;
  if (idx >= (long)NB * NT * NH) return;
  int h = (int)(idx % NH);
  float qv = q[idx], pv = p[idx];
  uint16_t qh = f2bf(qv);
  q_hi[idx] = qh; q_lo[idx] = f2bf(qv - bf2f(qh));
  uint16_t ph = f2bf(pv);
  p_hi[idx] = ph; p_lo[idx] = f2bf(pv - bf2f(ph));
  pd[idx] = f2bf(pv * Wd[h]);
}

// qT[b,h,t] = q_hi[b,t,h]  (LDS-tiled transpose, 32x32 tiles)
__global__ void transpose_q(const uint16_t* __restrict__ q_hi, uint16_t* __restrict__ qT) {
  __shared__ uint16_t tile[32][33];
  int b = blockIdx.z;
  int h0 = blockIdx.x * 32, t0 = blockIdx.y * 32;
  int tx = threadIdx.x & 31, ty = threadIdx.x >> 5;  // ty in [0,8)
  const uint16_t* src = q_hi + ((long)b * NT + t0) * NH + h0;
  for (int s = 0; s < 32; s += 8) tile[ty + s][tx] = src[(long)(ty + s) * NH + tx];
  __syncthreads();
  uint16_t* dst = qT + ((long)b * NH + h0) * NT + t0;
  for (int s = 0; s < 32; s += 8) dst[(long)(ty + s) * NT + tx] = tile[tx][ty + s];
}

// qWm[b,t] = q[b,t,:]·Wm ; pWm[b,t] = p[b,t,:]·Wm  (f32 exact)
__global__ void gemv_wm(const float* __restrict__ q, const float* __restrict__ p,
                        const float* __restrict__ Wm,
                        float* __restrict__ qWm, float* __restrict__ pWm) {
  int wave = (blockIdx.x * 256 + (int)threadIdx.x) >> 6;
  int lane = threadIdx.x & 63;
  const int nrows = NB * NT;
  const float* src = (wave < nrows) ? q : p;
  float* dst = (wave < nrows) ? qWm : pWm;
  int row = (wave < nrows) ? wave : wave - nrows;
  const float* rp = src + (long)row * NH;
  float s = 0.f;
  for (int h = lane; h < NH; h += 64) s += rp[h] * Wm[h];
  for (int off = 32; off; off >>= 1) s += __shfl_down(s, off);
  if (lane == 0) dst[row] = s;
}

// ---------------------------------------------------------------------------
// Tiled batched NT GEMM (m97 structure): C[b] = sum_t A_t[b] (M,K)·B_t[b] (N,K)^T
// 128x128 block tile, 4 waves x (4x4) 16x16x32 bf16 MFMA, BK=32,
// global_load_lds width-16 staging, 2-barrier K-loop, ds_read_b128 frags.
// M,N multiples of 128; K multiple of 32; rows 16B-aligned.
// outmode: 0 = f32, 1 = bf16, 2 = bf16 hi/lo split to C0/C1.
__global__ __launch_bounds__(256) void gemm_tile(
    const uint16_t* __restrict__ A0, const uint16_t* __restrict__ A1,
    const uint16_t* __restrict__ A2,
    const uint16_t* __restrict__ B0, const uint16_t* __restrict__ B1,
    const uint16_t* __restrict__ B2,
    int npairs, long sA, long sB,
    int K, int lda, int ldb,
    int outmode, void* C0v, void* C1v, long sC, int ldc) {
  __shared__ __align__(16) uint16_t As[BM * BK];  // row-major [128][32]
  __shared__ __align__(16) uint16_t Bs[BN * BK];
  const int b = blockIdx.z;
  const int tid = threadIdx.x;
  const int wave = tid >> 6, lane = tid & 63;
  const int r = lane & 15, quad = lane >> 4;
  const int wm = wave >> 1, wn = wave & 1;
  const long tile_m = (long)blockIdx.y * BM;
  const long tile_n = (long)blockIdx.x * BN;

  // Staging geometry: chunk c = wave + 4*issue covers LDS rows [c*16, c*16+16).
  // Lane L supplies row c*16 + L/4, k-quad (L%4)*8  (matches HW lane*16B dest).
  const int st_row = lane >> 2;        // 0..15
  const int st_k   = (lane & 3) * 8;   // 0,8,16,24

  f32x4 acc[4][4];
#pragma unroll
  for (int i = 0; i < 4; ++i)
#pragma unroll
    for (int j = 0; j < 4; ++j) acc[i][j] = (f32x4){0.f, 0.f, 0.f, 0.f};

  for (int t = 0; t < npairs; ++t) {
    const uint16_t* Ap = (t == 0) ? A0 : ((t == 1) ? A1 : A2);
    const uint16_t* Bp = (t == 0) ? B0 : ((t == 1) ? B1 : B2);
    const uint16_t* Abase = Ap + (long)b * sA + tile_m * lda;
    const uint16_t* Bbase = Bp + (long)b * sB + tile_n * ldb;
    for (int k0 = 0; k0 < K; k0 += BK) {
      __syncthreads();  // previous iter's frag reads done before overwrite
      {
        int c0 = wave, c1 = wave + 4;
        gload_lds16(Abase + (long)(c0 * 16 + st_row) * lda + k0 + st_k, &As[c0 * 512]);
        gload_lds16(Abase + (long)(c1 * 16 + st_row) * lda + k0 + st_k, &As[c1 * 512]);
        gload_lds16(Bbase + (long)(c0 * 16 + st_row) * ldb + k0 + st_k, &Bs[c0 * 512]);
        gload_lds16(Bbase + (long)(c1 * 16 + st_row) * ldb + k0 + st_k, &Bs[c1 * 512]);
      }
      __syncthreads();  // staging visible (compiler drains vmcnt before barrier)
      bf16x8 av[4], bv[4];
#pragma unroll
      for (int mi = 0; mi < 4; ++mi)
        av[mi] = *(const bf16x8*)&As[(wm * 64 + mi * 16 + r) * BK + quad * 8];
#pragma unroll
      for (int ni = 0; ni < 4; ++ni)
        bv[ni] = *(const bf16x8*)&Bs[(wn * 64 + ni * 16 + r) * BK + quad * 8];
#pragma unroll
      for (int mi = 0; mi < 4; ++mi)
#pragma unroll
        for (int ni = 0; ni < 4; ++ni)
          acc[mi][ni] = __builtin_amdgcn_mfma_f32_16x16x32_bf16(av[mi], bv[ni], acc[mi][ni], 0, 0, 0);
    }
  }

  // C/D frag: col = lane&15, row = quad*4 + t   [verified m89/m91]
#pragma unroll
  for (int mi = 0; mi < 4; ++mi) {
    long row = tile_m + wm * 64 + mi * 16 + quad * 4;
#pragma unroll
    for (int ni = 0; ni < 4; ++ni) {
      long col = tile_n + wn * 64 + ni * 16 + r;
      if (outmode == 0) {
        float* C = (float*)C0v + (long)b * sC;
#pragma unroll
        for (int t = 0; t < 4; ++t) C[(row + t) * ldc + col] = acc[mi][ni][t];
      } else if (outmode == 1) {
        uint16_t* C = (uint16_t*)C0v + (long)b * sC;
#pragma unroll
        for (int t = 0; t < 4; ++t) C[(row + t) * ldc + col] = f2bf(acc[mi][ni][t]);
      } else {
        uint16_t* Ch = (uint16_t*)C0v + (long)b * sC;
        uint16_t* Cl = (uint16_t*)C1v + (long)b * sC;
#pragma unroll
        for (int t = 0; t < 4; ++t) {
          float v = acc[mi][ni][t];
          uint16_t hi = f2bf(v);
          Ch[(row + t) * ldc + col] = hi;
          Cl[(row + t) * ldc + col] = f2bf(v - bf2f(hi));
        }
      }
    }
  }
}

// ---------------------------------------------------------------------------
// One wave per (b,i) row: assemble 4 score rows, shuffle-reduce softmax, emit bf16 P.
// P layout: 4 contiguous [NB,NT,NT] blocks in order c,b,d,m.
__global__ __launch_bounds__(64) void softmax_k(
    const uint16_t* __restrict__ whp, const uint16_t* __restrict__ whqT,
    const float* __restrict__ sb, const uint16_t* __restrict__ sd,
    const float* __restrict__ qWm, const float* __restrict__ pWm,
    const float* __restrict__ vc, const float* __restrict__ vd,
    const float* __restrict__ vm,
    uint16_t* __restrict__ P) {
  int bi = blockIdx.x;  // b*NT + i
  int b = bi >> 8, i = bi & 255;
  int lane = threadIdx.x;
  long rowoff = (long)bi * NT;
  const long PB = (long)NB * NT * NT;
  float vci = vc[i];
  float pwm = pWm[(long)b * NT + i];
  float vals[4][4];
#pragma unroll
  for (int u = 0; u < 4; ++u) {
    int j = lane + 64 * u;
    long off = rowoff + j;
    vals[0][u] = tanhf(bf2f(whp[off]) + bf2f(whqT[off])) * vci;   // vc per-i
    vals[1][u] = sb[off];                                          // raw bilinear
    vals[2][u] = tanhf(bf2f(sd[off])) * vd[j];                     // vd per-j
    vals[3][u] = tanhf(qWm[(long)b * NT + j] - pwm) * vm[j];       // vm per-j
  }
#pragma unroll
  for (int a = 0; a < 4; ++a) {
    float m = fmaxf(fmaxf(vals[a][0], vals[a][1]), fmaxf(vals[a][2], vals[a][3]));
    for (int o = 32; o; o >>= 1) m = fmaxf(m, __shfl_xor(m, o));
    float e[4], s = 0.f;
#pragma unroll
    for (int u = 0; u < 4; ++u) { e[u] = __expf(vals[a][u] - m); s += e[u]; }
    for (int o = 32; o; o >>= 1) s += __shfl_xor(s, o);
    float inv = 1.f / s;
#pragma unroll
    for (int u = 0; u < 4; ++u)
      P[a * PB + rowoff + lane + 64 * u] = f2bf(e[u] * inv);
  }
}

// ---------------------------------------------------------------------------
extern "C" void kernel_launch(void* const* d_in, const int* in_sizes, int n_in,
                              void* d_out, int out_size, void* d_ws, size_t ws_size,
                              hipStream_t stream) {
  const float* q   = (const float*)d_in[0];
  const float* p   = (const float*)d_in[1];
  const float* Wc1 = (const float*)d_in[2];
  const float* Wc2 = (const float*)d_in[3];
  const float* vc  = (const float*)d_in[4];
  const float* Wb  = (const float*)d_in[5];
  const float* Wd  = (const float*)d_in[6];
  const float* vd  = (const float*)d_in[7];
  const float* Wm  = (const float*)d_in[8];
  const float* vm  = (const float*)d_in[9];
  (void)in_sizes; (void)n_in; (void)out_size; (void)ws_size;

  char* ws = (char*)d_ws;
  size_t o = 0;
  auto alloc = [&](size_t bytes) -> char* {
    char* r = ws + o;
    o = (o + bytes + 255) & ~(size_t)255;
    return r;
  };
  const size_t nqp = (size_t)NB * NT * NH;   // 12.58M
  const size_t ntt = (size_t)NB * NT * NT;   // 4.19M

  uint16_t* Wc1T = (uint16_t*)alloc((size_t)NT * NH * 2);
  uint16_t* Wc2T = (uint16_t*)alloc((size_t)NT * NH * 2);
  uint16_t* WbTh = (uint16_t*)alloc((size_t)NH * NH * 2);
  uint16_t* WbTl = (uint16_t*)alloc((size_t)NH * NH * 2);
  uint16_t* q_hi = (uint16_t*)alloc(nqp * 2);
  uint16_t* q_lo = (uint16_t*)alloc(nqp * 2);
  uint16_t* p_hi = (uint16_t*)alloc(nqp * 2);
  uint16_t* p_lo = (uint16_t*)alloc(nqp * 2);
  uint16_t* pd   = (uint16_t*)alloc(nqp * 2);
  uint16_t* qT   = (uint16_t*)alloc(nqp * 2);
  float*    qWmB = (float*)alloc((size_t)NB * NT * 4);
  float*    pWmB = (float*)alloc((size_t)NB * NT * 4);
  uint16_t* whp  = (uint16_t*)alloc(ntt * 2);
  uint16_t* whqT = (uint16_t*)alloc(ntt * 2);
  uint16_t* pWbh = (uint16_t*)alloc(nqp * 2);
  uint16_t* pWbl = (uint16_t*)alloc(nqp * 2);
  float*    sbuf = (float*)alloc(ntt * 4);
  uint16_t* sd   = (uint16_t*)alloc(ntt * 2);
  uint16_t* P    = (uint16_t*)alloc(4 * ntt * 2);

  const long sQP = (long)NT * NH;  // per-batch stride of q/p/pWb/qT/out
  const long sTT = (long)NT * NT;

  prep_weights<<<dim3((NH * NH + 255) / 256), dim3(256), 0, stream>>>(
      Wc1, Wc2, Wb, Wc1T, Wc2T, WbTh, WbTl);
  prep_qp<<<dim3((unsigned)((nqp + 255) / 256)), dim3(256), 0, stream>>>(
      q, p, Wd, q_hi, q_lo, p_hi, p_lo, pd);
  transpose_q<<<dim3(NH / 32, NT / 32, NB), dim3(256), 0, stream>>>(q_hi, qT);
  gemv_wm<<<dim3(2 * NB * NT / 4), dim3(256), 0, stream>>>(q, p, Wm, qWmB, pWmB);

  // whqT[b,i,j] = sum_h Wc1[h,i] q[b,j,h]   (A = Wc1T shared, B = q_hi batched)
  gemm_tile<<<dim3(NT / BN, NT / BM, NB), dim3(256), 0, stream>>>(
      Wc1T, nullptr, nullptr, q_hi, nullptr, nullptr, 1,
      0L, sQP, 768, NH, NH, 1, whqT, nullptr, sTT, NT);

  // whp[b,i,j] = sum_h p[b,i,h] Wc2[h,j]    (A = p_hi batched, B = Wc2T shared)
  gemm_tile<<<dim3(NT / BN, NT / BM, NB), dim3(256), 0, stream>>>(
      p_hi, nullptr, nullptr, Wc2T, nullptr, nullptr, 1,
      sQP, 0L, 768, NH, NH, 1, whp, nullptr, sTT, NT);

  // pWb = p @ Wb with hi/lo split (3 products), epilogue re-splits to hi/lo bf16
  gemm_tile<<<dim3(NH / BN, NT / BM, NB), dim3(256), 0, stream>>>(
      p_hi, p_hi, p_lo, WbTh, WbTl, WbTh, 3,
      sQP, 0L, 768, NH, NH, 2, pWbh, pWbl, sQP, NH);

  // sb = pWb @ q^T with hi/lo split (3 products), f32 out (precision-critical)
  gemm_tile<<<dim3(NT / BN, NT / BM, NB), dim3(256), 0, stream>>>(
      pWbh, pWbh, pWbl, q_hi, q_lo, q_hi, 3,
      sQP, sQP, 768, NH, NH, 0, sbuf, nullptr, sTT, NT);

  // sd_raw = (p*Wd) @ q^T
  gemm_tile<<<dim3(NT / BN, NT / BM, NB), dim3(256), 0, stream>>>(
      pd, nullptr, nullptr, q_hi, nullptr, nullptr, 1,
      sQP, sQP, 768, NH, NH, 1, sd, nullptr, sTT, NT);

  softmax_k<<<dim3(NB * NT), dim3(64), 0, stream>>>(
      whp, whqT, sbuf, sd, qWmB, pWmB, vc, vd, vm, P);

  // PV: out_a = P_a @ q   (A = P_a [T,T], B = qT [H,T] per batch)
  float* out = (float*)d_out;
  for (int a = 0; a < 4; ++a) {
    gemm_tile<<<dim3(NH / BN, NT / BM, NB), dim3(256), 0, stream>>>(
        P + (size_t)a * ntt, nullptr, nullptr, qT, nullptr, nullptr, 1,
        sTT, sQP, 256, NT, NT, 0, out + (size_t)a * nqp, nullptr, sQP, NH);
  }
}